// Round 12
// baseline (93.242 us; speedup 1.0000x reference)
//
#include <hip/hip_runtime.h>

#define NT 1024
#define NS 2048
#define NH 32

// R12: one site per 64-lane wave, REDUNDANT HALVES (lane l and l+32 do
// identical work for h = l = tid&31). No LDS in the hot path:
//  - chunk inputs: each lane loads+preps t-offset l; per-step broadcast is
//    4x v_readlane(.., k) (synchronous VALU, no LDS pipe, no waitcnt games).
//  - y-reduction: register butterfly transpose-reduce (__shfl_xor, verified
//    R10), double-buffered, stages interleaved into the NEXT chunk's step
//    loop (k=2/8/14/20/26) so bpermute latency hides under step VALU.
//  - grid 512 blocks -> 2 waves/SIMD TLP covers residual latency.
// Per-step: 4 readlane + 10 VALU, all register-resident, compiler-safe.

#define RL(x, k) __int_as_float(__builtin_amdgcn_readlane(__float_as_int(x), k))

#define BSTAGE(z, o) { \
    _Pragma("unroll") \
    for (int j = 0; j < o; ++j) { \
        const bool up = (l & o) != 0; \
        const float send = up ? z[j] : z[j + o]; \
        const float keep = up ? z[j + o] : z[j]; \
        z[j] = keep + __shfl_xor(send, o); \
    } \
}

// One chunk: prep(C) -> prefetch loads(C+1) -> 32 steps (+ butterfly of ycP
// interleaved) -> store chunk C-1's result.
#define CHUNK_BODY(C, ycC, ycP, DO_PREV, DO_NEXT) { \
    prep(); \
    if (DO_NEXT) { \
        const size_t nb = base + (size_t)((C) + 1) * 32 * NS; \
        pp = P[nb]; ta = T1[nb]; tb = T2[nb]; ee = E[nb]; \
    } \
    _Pragma("unroll") \
    for (int k = 0; k < 32; ++k) { \
        const float sTaP = RL(vTaP, k); \
        const float sPs  = RL(vPs,  k); \
        const float sPl  = RL(vPl,  k); \
        const float sE   = RL(vE,   k); \
        const float bm = sTaP * gm; \
        const float t2 = sE * ge; \
        const float pw = sPl - t2; \
        const float Sm = fminf(S, bm); \
        const float t1 = fmaf(go1, r, pw); \
        r = fmaxf(t1 + Sm, 0.0f); \
        ycC[k] = r * gq; \
        S = (S + sPs) - Sm; \
        if (DO_PREV) { \
            if (k == 2)  { BSTAGE(ycP, 16) } \
            if (k == 8)  { BSTAGE(ycP, 8)  } \
            if (k == 14) { BSTAGE(ycP, 4)  } \
            if (k == 20) { BSTAGE(ycP, 2)  } \
            if (k == 26) { BSTAGE(ycP, 1)  } \
        } \
    } \
    if ((DO_PREV) && storeHalf) \
        Y[(size_t)(((C) - 1) * 32 + l) * NS + s] = ycP[0]; \
}

__global__ __launch_bounds__(256, 2)
void waternet_kernel(const float* __restrict__ P,
                     const float* __restrict__ T1,
                     const float* __restrict__ T2,
                     const float* __restrict__ E,
                     const float* __restrict__ w,
                     float* __restrict__ Y)
{
    const int tid = threadIdx.x;
    const int l   = tid & 31;          // h index AND t-offset (halves identical)
    const int wid = tid >> 6;          // wave in block [0,4)
    const bool storeHalf = (tid & 32) == 0;

    // XCD-contiguous site mapping (512 blocks, round-robin dispatch: bid%8 = XCD)
    const int bid    = blockIdx.x;
    const int sChunk = (bid & 7) * 64 + (bid >> 3);   // bijective [0,512)
    const int s      = sChunk * 4 + wid;              // [0,2048)

    // ---- per-h gate weights (one-time) ----
    const float gm = expf(w[l]) + 1.0f;
    const float ge = 1.0f / (1.0f + expf(-w[NH + l]));
    const float go = 1.0f / (1.0f + expf(-w[2 * NH + l]));
    const float wa = w[3 * NH + l];

    float mx = wa;
    #pragma unroll
    for (int o = 16; o; o >>= 1) mx = fmaxf(mx, __shfl_xor(mx, o));
    float ea = expf(wa - mx);
    float ssum = ea;
    #pragma unroll
    for (int o = 16; o; o >>= 1) ssum += __shfl_xor(ssum, o);
    const float ga  = ea / ssum;
    const float go1 = 1.0f - go;   // r' = max(go1*r + pw + Sm, 0)
    const float gq  = go * ga;     // y-contrib = r*gq

    float S = 0.0f, r = 0.0f;

    // chunk-0 input loads: lane covers t = l (halves load same addresses)
    const size_t base = (size_t)l * NS + s;
    float pp = P[base], ta = T1[base], tb = T2[base], ee = E[base];

    float vTaP, vPs, vPl, vE;   // prepped per-t values for the current chunk

    auto prep = [&]() {
        const float sum   = ta + tb;                   // 2*Ta
        float ratio = sum / (tb - ta);                 // tb > ta guaranteed
        ratio = fminf(fmaxf(ratio, -1.0f), 1.0f);
        float rP = 1.0f - acosf(ratio) * (1.0f / 3.1415f);
        if (ta >= 0.0f) rP = 1.0f;
        if (tb <= 0.0f) rP = 0.0f;
        vPl  = rP * pp;
        vPs  = pp - vPl;                               // (1-rP)*P
        vTaP = fmaxf(sum * 0.5f, 0.0f);                // gm>0: max(Ta*gm,0)=TaP*gm
        vE   = ee;
    };

    float ycA[32], ycB[32];

    #pragma unroll 1
    for (int c = 0; c < 32; c += 2) {
        CHUNK_BODY(c,     ycA, ycB, (c > 0), true)
        CHUNK_BODY(c + 1, ycB, ycA, true,    ((c + 1) < 31))
    }

    // epilogue: butterfly + store for chunk 31 (in ycB)
    BSTAGE(ycB, 16)
    BSTAGE(ycB, 8)
    BSTAGE(ycB, 4)
    BSTAGE(ycB, 2)
    BSTAGE(ycB, 1)
    if (storeHalf) Y[(size_t)(31 * 32 + l) * NS + s] = ycB[0];
}

extern "C" void kernel_launch(void* const* d_in, const int* in_sizes, int n_in,
                              void* d_out, int out_size, void* d_ws, size_t ws_size,
                              hipStream_t stream) {
    const float* P  = (const float*)d_in[0];
    const float* T1 = (const float*)d_in[1];
    const float* T2 = (const float*)d_in[2];
    const float* E  = (const float*)d_in[3];
    const float* w  = (const float*)d_in[4];
    float* Y = (float*)d_out;

    waternet_kernel<<<dim3(512), dim3(256), 0, stream>>>(P, T1, T2, E, w, Y);
}

// Round 13
// 92.386 us; speedup vs baseline: 1.0093x; 1.0093x over previous
//
#include <hip/hip_runtime.h>

#define NT 1024
#define NS 2048
#define NH 32
#define INV_PI (1.0f / 3.1415f)

// ============================================================================
// R13: time-block-parallel reformulation.
//   S' = max(S - bm, 0) + Ps  ==  max(S - beta, gamma), beta = bm - Ps,
//   gamma = Ps; composition closed: B += beta, Gam = max(Gam - beta, gamma).
//   H' = max(alpha*H + a, 0), alpha = 1-go <= 0.731 -> alpha^32 <= 4.4e-5:
//   H warm-up of 32 steps is provably within 0.04 absolute.
// K1: per (32-step block jb, site s): composed S-function per h.
// K2: per (h, s): exact prefix scan over the 32 blocks -> S at block starts.
// K3: per (64-step block tb, s, h-half): 32-step warm-up + 64 emit steps,
//     h vectorized in registers (16/lane), pair-sum via DPP quad_perm.
// No LDS anywhere; all loads coalesced (lane = s); no cross-lane in hot loop.
// ============================================================================

__device__ __forceinline__ void prep_step(float p, float a, float b,
                                          float& TaP, float& Ps, float& Pl) {
    float sum   = a + b;                       // 2*Ta
    float ratio = sum / (b - a);               // b > a guaranteed
    ratio = fminf(fmaxf(ratio, -1.0f), 1.0f);
    float rP = 1.0f - acosf(ratio) * INV_PI;
    if (a >= 0.0f) rP = 1.0f;
    if (b <= 0.0f) rP = 0.0f;
    Pl  = rP * p;
    Ps  = p - Pl;                              // (1-rP)*P
    TaP = fmaxf(sum * 0.5f, 0.0f);             // gm>0: max(Ta*gm,0) = TaP*gm
}

// ---------------- K1: S-function per (jb, s) ----------------
__global__ __launch_bounds__(256, 1)
void k1_sfunc(const float* __restrict__ P, const float* __restrict__ T1,
              const float* __restrict__ T2, const float* __restrict__ w,
              float* __restrict__ ws)
{
    const int gtid = blockIdx.x * 256 + threadIdx.x;   // 65536
    const int jb   = gtid >> 11;                        // [0,32)
    const int s    = gtid & (NS - 1);

    float gm[NH];
    #pragma unroll
    for (int h = 0; h < NH; ++h) gm[h] = expf(w[h]) + 1.0f;

    float G[NH];
    #pragma unroll
    for (int h = 0; h < NH; ++h) G[h] = -3.0e38f;
    float aT = 0.0f, aP = 0.0f;

    size_t idx = (size_t)(jb * 32) * NS + s;
    float p = P[idx], a = T1[idx], b = T2[idx];

    for (int k = 0; k < 32; ++k) {
        float pn = 0.f, an = 0.f, bn = 1.f;
        if (k < 31) {
            size_t nx = idx + (size_t)(k + 1) * NS;
            pn = P[nx]; an = T1[nx]; bn = T2[nx];
        }
        float TaP, Ps, Pl;
        prep_step(p, a, b, TaP, Ps, Pl);
        aT += TaP; aP += Ps;
        #pragma unroll
        for (int h = 0; h < NH; ++h) {
            float beta = fmaf(TaP, gm[h], -Ps);
            G[h] = fmaxf(G[h] - beta, Ps);
        }
        p = pn; a = an; b = bn;
    }

    #pragma unroll
    for (int h = 0; h < NH; ++h) {
        float B = fmaf(aT, gm[h], -aP);
        size_t o = ((size_t)(jb * NH + h) * 2) * NS + s;
        ws[o]      = B;
        ws[o + NS] = G[h];
    }
}

// ---------------- K2: exact S prefix scan over blocks ----------------
__global__ __launch_bounds__(256, 1)
void k2_scan(float* __restrict__ ws)
{
    const int gtid = blockIdx.x * 256 + threadIdx.x;   // 65536
    const int h    = gtid >> 11;                        // [0,32)
    const int s    = gtid & (NS - 1);

    float Bv[32], Gv[32];
    #pragma unroll
    for (int jb = 0; jb < 32; ++jb) {
        size_t o = ((size_t)(jb * NH + h) * 2) * NS + s;
        Bv[jb] = ws[o];
        Gv[jb] = ws[o + NS];
    }
    float S = 0.0f;
    #pragma unroll
    for (int jb = 0; jb < 32; ++jb) {
        size_t o = ((size_t)(jb * NH + h) * 2) * NS + s;
        ws[o] = S;                            // S at start of block jb
        S = fmaxf(S - Bv[jb], Gv[jb]);
    }
}

// ---------------- K3: warm-up + emit, h in registers ----------------
__global__ __launch_bounds__(256, 1)
void k3_emit(const float* __restrict__ P, const float* __restrict__ T1,
             const float* __restrict__ T2, const float* __restrict__ E,
             const float* __restrict__ w, const float* __restrict__ ws,
             float* __restrict__ Y)
{
    const int gtid = blockIdx.x * 256 + threadIdx.x;   // 65536
    const int pair = gtid >> 1;
    const int hh   = gtid & 1;                          // h-half
    const int tb   = pair >> 11;                        // 64-step block [0,16)
    const int s    = pair & (NS - 1);

    // gates for h = hh*16 + i
    float gm[16], ge[16], al[16], gq[16];
    float esum = 0.0f;
    #pragma unroll
    for (int i = 0; i < 16; ++i) {
        int h = hh * 16 + i;
        gm[i] = expf(w[h]) + 1.0f;
        ge[i] = 1.0f / (1.0f + expf(-w[NH + h]));
        float go = 1.0f / (1.0f + expf(-w[2 * NH + h]));
        al[i] = 1.0f - go;
        float ea = expf(w[3 * NH + h]);
        gq[i] = go * ea;
        esum += ea;
    }
    {   // pair-exchange esum (quad_perm [1,0,3,2] = xor 1)
        int t = __builtin_amdgcn_update_dpp(0, __float_as_int(esum), 0xB1, 0xf, 0xf, false);
        esum += __int_as_float(t);
    }
    const float inv = 1.0f / esum;
    #pragma unroll
    for (int i = 0; i < 16; ++i) gq[i] *= inv;

    float S[16], H[16];
    #pragma unroll
    for (int i = 0; i < 16; ++i) H[i] = 0.0f;

    int t0;
    if (tb == 0) {
        t0 = 0;
        #pragma unroll
        for (int i = 0; i < 16; ++i) S[i] = 0.0f;
    } else {
        t0 = tb * 64 - 32;
        const int jb = tb * 2 - 1;                      // 32-block starting at t0
        #pragma unroll
        for (int i = 0; i < 16; ++i) {
            int h = hh * 16 + i;
            S[i] = ws[((size_t)(jb * NH + h) * 2) * NS + s];
        }
    }
    const int temit = tb * 64;
    const int tend  = tb * 64 + 64;

    size_t idx = (size_t)t0 * NS + s;
    float p = P[idx], a = T1[idx], b = T2[idx], e = E[idx];

    #pragma unroll 1
    for (int t = t0; t < tend; ++t) {
        float pn = 0.f, an = 0.f, bn = 1.f, en = 0.f;
        if (t + 1 < tend) {
            size_t nx = idx + NS;
            pn = P[nx]; an = T1[nx]; bn = T2[nx]; en = E[nx];
        }
        float TaP, Ps, Pl;
        prep_step(p, a, b, TaP, Ps, Pl);

        float acc = 0.0f;
        #pragma unroll
        for (int i = 0; i < 16; ++i) {
            float bm  = TaP * gm[i];
            float Sm  = fminf(S[i], bm);
            float t1h = fmaf(al[i], H[i], Sm);
            float t2h = fmaf(-ge[i], e, Pl);
            float Hn  = fmaxf(t1h + t2h, 0.0f);
            H[i] = Hn;
            S[i] = (S[i] - Sm) + Ps;
            acc  = fmaf(Hn, gq[i], acc);
        }

        if (t >= temit) {   // uniform per block
            int tr = __builtin_amdgcn_update_dpp(0, __float_as_int(acc), 0xB1, 0xf, 0xf, false);
            float ytot = acc + __int_as_float(tr);
            if (hh == 0) Y[(size_t)t * NS + s] = ytot;
        }

        p = pn; a = an; b = bn; e = en;
        idx += NS;
    }
}

// ---------------- fallback (R10, verified 50.6us) if ws too small ----------
typedef float f32x4 __attribute__((ext_vector_type(4)));

__global__ __launch_bounds__(256, 1)
void waternet_fallback(const float* __restrict__ P, const float* __restrict__ T1,
                       const float* __restrict__ T2, const float* __restrict__ E,
                       const float* __restrict__ w, float* __restrict__ Y)
{
    const int tid  = threadIdx.x;
    const int lane = tid & 31;
    const int grp  = tid >> 5;
    const int bid    = blockIdx.x;
    const int sChunk = (bid & 7) * 32 + (bid >> 3);
    const int s      = sChunk * 8 + grp;

    const float gm = expf(w[lane]) + 1.0f;
    const float ge = 1.0f / (1.0f + expf(-w[NH + lane]));
    const float go = 1.0f / (1.0f + expf(-w[2 * NH + lane]));
    const float wa = w[3 * NH + lane];
    float mx = wa;
    #pragma unroll
    for (int o = 16; o; o >>= 1) mx = fmaxf(mx, __shfl_xor(mx, o));
    float ea = expf(wa - mx);
    float ssum = ea;
    #pragma unroll
    for (int o = 16; o; o >>= 1) ssum += __shfl_xor(ssum, o);
    const float ga  = ea / ssum;
    const float go1 = 1.0f - go;
    const float gq  = go * ga;

    float S = 0.0f, Hs = 0.0f;
    __shared__ f32x4 stage[8][32];
    const unsigned lds_base = (unsigned)(size_t)&stage[grp][0];

    size_t base = (size_t)lane * NS + s;
    float p0 = P[base], a0 = T1[base], b0 = T2[base], e0 = E[base];
    size_t bn = base + (size_t)32 * NS;
    float pg = P[bn], ag = T1[bn], bg = T2[bn], eg = E[bn];

    auto prep = [&](float p, float ta, float tb, float ee) {
        float TaP, Ps, Pl;
        prep_step(p, ta, tb, TaP, Ps, Pl);
        f32x4 v; v.x = TaP; v.y = Ps; v.z = Pl; v.w = ee;
        stage[grp][lane] = v;
    };
    prep(p0, a0, b0, e0);

    #pragma unroll 1
    for (int c = 0; c < 32; ++c) {
        f32x4 x[32];
        #pragma unroll
        for (int j = 0; j < 32; ++j) {
            asm volatile("ds_read_b128 %0, %1"
                         : "=v"(x[j]) : "v"(lds_base + (unsigned)(j * 16)) : "memory");
        }
        asm volatile("s_waitcnt lgkmcnt(0)" ::: "memory");
        __builtin_amdgcn_sched_barrier(0);

        if (c < 31) prep(pg, ag, bg, eg);
        if (c < 30) {
            size_t nb = base + (size_t)(c + 2) * 32 * NS;
            pg = P[nb]; ag = T1[nb]; bg = T2[nb]; eg = E[nb];
        }

        float ycon[32];
        #pragma unroll
        for (int k = 0; k < 32; ++k) {
            const f32x4 xx = x[k];
            const float bm = xx.x * gm;
            const float pw = fmaf(-xx.w, ge, xx.z);
            const float Sm = fminf(S, bm);
            const float Sp = S + xx.y;
            const float h3 = fmaxf(Hs + (pw + Sm), 0.0f);
            S  = Sp - Sm;
            Hs = h3 * go1;
            ycon[k] = h3 * gq;
        }
        #pragma unroll
        for (int o = 16; o >= 1; o >>= 1) {
            #pragma unroll
            for (int j = 0; j < 16; ++j) {
                if (j < o) {
                    const float lo = ycon[j];
                    const float hi = ycon[j + o];
                    const float send = (lane & o) ? lo : hi;
                    const float keep = (lane & o) ? hi : lo;
                    ycon[j] = keep + __shfl_xor(send, o);
                }
            }
        }
        Y[(size_t)(c * 32 + lane) * NS + s] = ycon[0];
    }
}

// ---------------- launcher ----------------
extern "C" void kernel_launch(void* const* d_in, const int* in_sizes, int n_in,
                              void* d_out, int out_size, void* d_ws, size_t ws_size,
                              hipStream_t stream) {
    const float* P  = (const float*)d_in[0];
    const float* T1 = (const float*)d_in[1];
    const float* T2 = (const float*)d_in[2];
    const float* E  = (const float*)d_in[3];
    const float* w  = (const float*)d_in[4];
    float* Y  = (float*)d_out;
    float* ws = (float*)d_ws;

    const size_t need = (size_t)32 * NH * 2 * NS * sizeof(float);   // 16 MiB
    if (ws_size >= need) {
        k1_sfunc<<<dim3(256), dim3(256), 0, stream>>>(P, T1, T2, w, ws);
        k2_scan <<<dim3(256), dim3(256), 0, stream>>>(ws);
        k3_emit <<<dim3(256), dim3(256), 0, stream>>>(P, T1, T2, E, w, ws, Y);
    } else {
        waternet_fallback<<<dim3(256), dim3(256), 0, stream>>>(P, T1, T2, E, w, Y);
    }
}